// Round 7
// baseline (188.600 us; speedup 1.0000x reference)
//
#include <hip/hip_runtime.h>

// BackwardRPM: 16384 independent solves, 200 steps of
//   u <- clip(u - LR * (R^T (R (tanh(u W1 + b1) W2 + b2 - spec)))[:6])
// Algebra: Qs[i][j] = -LR sum_p M_i[p] R[p][j], M_i[p] = sum_k W2[i][k]R[p][k]
//   es[j] = -LR sum_p R[p][j] z[p], z[p] = sum_k R[p][k](b2[k]-spec[k])
//   u <- med3(u + es + sum_i tanh(t_i) Qs[i,:], 0, 1), t = u W1 + b1
//
// R7 (from R6 calibration: trans ~16cyc serializes with VALU; pk_fma no gain):
//  * tanh via Pade(5,4): t(945+105s+s^2)/(945+420s+15s^2), s=t^2. |t|<=2.25
//    here (err ~3e-5); kills all v_exp.
//  * quad batch-inversion: 2 rcp instead of 8 per wave-step.
//  * v_dot2_f32_f16 for both MAC blocks (f16-packed W1, Qs, u, tanh):
//    48+48 FMA -> 24+24 dot2.
//  * Same R6 skeleton: whole loop one asm block, hard regs v0-v124,
//    8 lanes/sample, 2048 waves = 2/SIMD, DPP 3-stage allreduce.
//
// ws u32 layout: per-lane slice (sub<8) at [sub*56]:
//   [0..23]  w1h[ii][jp] = pk_f16(W1[2jp][ib+ii], W1[2jp+1][ib+ii])
//   [24..47] qh[p][j]    = pk_f16(Qs[ib+2p][j], Qs[ib+2p+1][j])
//   [48..55] b1[ib+ii] (f32 bits)
// [448..455] (R b2)[p] (f32 bits)

static constexpr float LR_ = 0.01f;

static __device__ __forceinline__ unsigned int pk2(float a, float b) {
    union { _Float16 h; unsigned short u; } ca, cb;
    ca.h = (_Float16)a; cb.h = (_Float16)b;            // RNE converts
    return (unsigned int)ca.u | ((unsigned int)cb.u << 16);
}

__global__ void setup_k(const float* __restrict__ W1, const float* __restrict__ b1,
                        const float* __restrict__ W2, const float* __restrict__ b2,
                        const float* __restrict__ R,  unsigned int* __restrict__ ws)
{
    const int t = threadIdx.x;
    if (t < 64) {                       // unit i: W1 pairs + b1
        const int i = t, sl = (i >> 3) * 56, ii = i & 7;
        #pragma unroll
        for (int jp = 0; jp < 3; ++jp)
            ws[sl + ii*3 + jp] = pk2(W1[(2*jp)*64 + i], W1[(2*jp+1)*64 + i]);
        ws[sl + 48 + ii] = __float_as_uint(b1[i]);
    } else if (t < 96) {                // unit pair P: Qs pairs
        const int P = t - 64;           // units 2P, 2P+1
        float Q[2][6];
        #pragma unroll
        for (int h = 0; h < 2; ++h) {
            const int i = 2*P + h;
            float M[8];
            #pragma unroll
            for (int p = 0; p < 8; ++p) {
                float acc = 0.f;
                for (int k = 0; k < 40; ++k) acc = fmaf(W2[i*40+k], R[p*40+k], acc);
                M[p] = acc;
            }
            #pragma unroll
            for (int j = 0; j < 6; ++j) {
                float acc = 0.f;
                #pragma unroll
                for (int p = 0; p < 8; ++p) acc = fmaf(M[p], R[p*40+j], acc);
                Q[h][j] = -LR_ * acc;
            }
        }
        const int sl = (P >> 2) * 56, pp = P & 3;
        #pragma unroll
        for (int j = 0; j < 6; ++j)
            ws[sl + 24 + pp*6 + j] = pk2(Q[0][j], Q[1][j]);
    } else if (t < 104) {               // (R b2)[p]
        const int p = t - 96;
        float acc = 0.f;
        for (int k = 0; k < 40; ++k) acc = fmaf(R[p*40+k], b2[k], acc);
        ws[448 + p] = __float_as_uint(acc);
    }
}

__global__ __launch_bounds__(256, 2) void solve_k(
    const float* __restrict__ spec, const float* __restrict__ R,
    const unsigned int* __restrict__ ws, float* __restrict__ out, int batch)
{
    const int tid = blockIdx.x * 256 + threadIdx.x;
    const int s   = tid >> 3;
    const int sub = tid & 7;
    const bool live = (s < batch);
    const int sl = live ? s : 0;

    // z[p] = (R b2)[p] - sum_k R[p][k] spec[k]
    float z[8];
    #pragma unroll
    for (int p = 0; p < 8; ++p) z[p] = __uint_as_float(ws[448 + p]);
    const float* sp = spec + sl * 40;
    for (int k = 0; k < 40; ++k) {
        float v = sp[k];
        #pragma unroll
        for (int p = 0; p < 8; ++p) z[p] = fmaf(-R[p*40+k], v, z[p]);
    }
    // ec[j] = es[j]/8 = -(LR/8) sum_p R[p][j] z[p]
    float ec[6];
    #pragma unroll
    for (int j = 0; j < 6; ++j) {
        float acc = 0.f;
        #pragma unroll
        for (int p = 0; p < 8; ++p) acc = fmaf(R[p*40+j], z[p], acc);
        ec[j] = -LR_ * 0.125f * acc;
    }

    const unsigned int* pw = ws + sub * 56;   // 224 B slice, 16B-aligned

    float o0, o1, o2, o3, o4, o5;
    // Register map: v0-5 g | v6-13 t | v14-21 s | v22-29 den->inv | v30-37 num->tanh
    // v38-45 qinv temps | v46-49 tanh f16 pairs | v50-55 u | v56 945 v57 15 v58 420
    // v59-61 u f16 pairs (also qinv temps) | v62-67 ec | v68-91 w1h | v92-115 qh
    // v116-123 b1 | v124 0.125
    asm volatile(
        "global_load_dwordx4 v[68:71],   %[pw], off            \n"
        "global_load_dwordx4 v[72:75],   %[pw], off offset:16  \n"
        "global_load_dwordx4 v[76:79],   %[pw], off offset:32  \n"
        "global_load_dwordx4 v[80:83],   %[pw], off offset:48  \n"
        "global_load_dwordx4 v[84:87],   %[pw], off offset:64  \n"
        "global_load_dwordx4 v[88:91],   %[pw], off offset:80  \n"
        "global_load_dwordx4 v[92:95],   %[pw], off offset:96  \n"
        "global_load_dwordx4 v[96:99],   %[pw], off offset:112 \n"
        "global_load_dwordx4 v[100:103], %[pw], off offset:128 \n"
        "global_load_dwordx4 v[104:107], %[pw], off offset:144 \n"
        "global_load_dwordx4 v[108:111], %[pw], off offset:160 \n"
        "global_load_dwordx4 v[112:115], %[pw], off offset:176 \n"
        "global_load_dwordx4 v[116:119], %[pw], off offset:192 \n"
        "global_load_dwordx4 v[120:123], %[pw], off offset:208 \n"
        "v_mov_b32 v56, 0x446c4000 \n"   // 945.0
        "v_mov_b32 v57, 0x41700000 \n"   // 15.0
        "v_mov_b32 v58, 0x43d20000 \n"   // 420.0
        "v_mov_b32 v124, 0x3e000000 \n"  // 0.125
        "v_mov_b32 v62, %[e0] \n v_mov_b32 v63, %[e1] \n v_mov_b32 v64, %[e2] \n"
        "v_mov_b32 v65, %[e3] \n v_mov_b32 v66, %[e4] \n v_mov_b32 v67, %[e5] \n"
        "v_mov_b32 v50, 0.5 \n v_mov_b32 v51, 0.5 \n v_mov_b32 v52, 0.5 \n"
        "v_mov_b32 v53, 0.5 \n v_mov_b32 v54, 0.5 \n v_mov_b32 v55, 0.5 \n"
        "s_mov_b32 s90, 200 \n"
        "s_waitcnt vmcnt(0) \n"
        "L_step_%=: \n"
        // pack u into f16 pairs
        "v_cvt_pkrtz_f16_f32 v59, v50, v51 \n"
        "v_cvt_pkrtz_f16_f32 v60, v52, v53 \n"
        "v_cvt_pkrtz_f16_f32 v61, v54, v55 \n"
        // t = u W1 + b1  (dot2 over j-pairs; jp outer, unit inner)
        "v_dot2_f32_f16 v6,  v59, v68, v116 \n v_dot2_f32_f16 v7,  v59, v71, v117 \n"
        "v_dot2_f32_f16 v8,  v59, v74, v118 \n v_dot2_f32_f16 v9,  v59, v77, v119 \n"
        "v_dot2_f32_f16 v10, v59, v80, v120 \n v_dot2_f32_f16 v11, v59, v83, v121 \n"
        "v_dot2_f32_f16 v12, v59, v86, v122 \n v_dot2_f32_f16 v13, v59, v89, v123 \n"
        "v_dot2_f32_f16 v6,  v60, v69, v6  \n v_dot2_f32_f16 v7,  v60, v72, v7  \n"
        "v_dot2_f32_f16 v8,  v60, v75, v8  \n v_dot2_f32_f16 v9,  v60, v78, v9  \n"
        "v_dot2_f32_f16 v10, v60, v81, v10 \n v_dot2_f32_f16 v11, v60, v84, v11 \n"
        "v_dot2_f32_f16 v12, v60, v87, v12 \n v_dot2_f32_f16 v13, v60, v90, v13 \n"
        "v_dot2_f32_f16 v6,  v61, v70, v6  \n v_dot2_f32_f16 v7,  v61, v73, v7  \n"
        "v_dot2_f32_f16 v8,  v61, v76, v8  \n v_dot2_f32_f16 v9,  v61, v79, v9  \n"
        "v_dot2_f32_f16 v10, v61, v82, v10 \n v_dot2_f32_f16 v11, v61, v85, v11 \n"
        "v_dot2_f32_f16 v12, v61, v88, v12 \n v_dot2_f32_f16 v13, v61, v91, v13 \n"
        // s = t*t
        "v_mul_f32 v14, v6, v6   \n v_mul_f32 v15, v7, v7   \n"
        "v_mul_f32 v16, v8, v8   \n v_mul_f32 v17, v9, v9   \n"
        "v_mul_f32 v18, v10, v10 \n v_mul_f32 v19, v11, v11 \n"
        "v_mul_f32 v20, v12, v12 \n v_mul_f32 v21, v13, v13 \n"
        // den = 945 + 420 s + 15 s^2
        "v_fma_f32 v22, v14, v57, v58 \n v_fma_f32 v23, v15, v57, v58 \n"
        "v_fma_f32 v24, v16, v57, v58 \n v_fma_f32 v25, v17, v57, v58 \n"
        "v_fma_f32 v26, v18, v57, v58 \n v_fma_f32 v27, v19, v57, v58 \n"
        "v_fma_f32 v28, v20, v57, v58 \n v_fma_f32 v29, v21, v57, v58 \n"
        "v_fma_f32 v22, v14, v22, v56 \n v_fma_f32 v23, v15, v23, v56 \n"
        "v_fma_f32 v24, v16, v24, v56 \n v_fma_f32 v25, v17, v25, v56 \n"
        "v_fma_f32 v26, v18, v26, v56 \n v_fma_f32 v27, v19, v27, v56 \n"
        "v_fma_f32 v28, v20, v28, v56 \n v_fma_f32 v29, v21, v29, v56 \n"
        // num = t*(945 + 105 s + s^2)
        "v_add_f32 v30, 0x42d20000, v14 \n v_add_f32 v31, 0x42d20000, v15 \n"
        "v_add_f32 v32, 0x42d20000, v16 \n v_add_f32 v33, 0x42d20000, v17 \n"
        "v_add_f32 v34, 0x42d20000, v18 \n v_add_f32 v35, 0x42d20000, v19 \n"
        "v_add_f32 v36, 0x42d20000, v20 \n v_add_f32 v37, 0x42d20000, v21 \n"
        "v_fma_f32 v30, v14, v30, v56 \n v_fma_f32 v31, v15, v31, v56 \n"
        "v_fma_f32 v32, v16, v32, v56 \n v_fma_f32 v33, v17, v33, v56 \n"
        "v_fma_f32 v34, v18, v34, v56 \n v_fma_f32 v35, v19, v35, v56 \n"
        "v_fma_f32 v36, v20, v36, v56 \n v_fma_f32 v37, v21, v37, v56 \n"
        "v_mul_f32 v30, v6, v30  \n v_mul_f32 v31, v7, v31  \n"
        "v_mul_f32 v32, v8, v32  \n v_mul_f32 v33, v9, v33  \n"
        "v_mul_f32 v34, v10, v34 \n v_mul_f32 v35, v11, v35 \n"
        "v_mul_f32 v36, v12, v36 \n v_mul_f32 v37, v13, v37 \n"
        // g init = 0.125*u + ec  (independent; fills rcp shadow)
        "v_fma_f32 v0, v124, v50, v62 \n v_fma_f32 v1, v124, v51, v63 \n"
        "v_fma_f32 v2, v124, v52, v64 \n v_fma_f32 v3, v124, v53, v65 \n"
        "v_fma_f32 v4, v124, v54, v66 \n v_fma_f32 v5, v124, v55, v67 \n"
        // quad inversion: dens v22-25 (A), v26-29 (B) -> inverses in place
        "v_mul_f32 v38, v22, v23 \n v_mul_f32 v42, v26, v27 \n"
        "v_mul_f32 v39, v38, v24 \n v_mul_f32 v43, v42, v28 \n"
        "v_mul_f32 v40, v39, v25 \n v_mul_f32 v44, v43, v29 \n"
        "v_rcp_f32 v41, v40 \n v_rcp_f32 v45, v44 \n"
        "v_mul_f32 v59, v41, v25 \n v_mul_f32 v60, v45, v29 \n"  // c2 = 1/(d0d1d2)
        "v_mul_f32 v25, v41, v39 \n v_mul_f32 v29, v45, v43 \n"  // inv3
        "v_mul_f32 v41, v59, v24 \n v_mul_f32 v45, v60, v28 \n"  // c1 = 1/(d0d1)
        "v_mul_f32 v24, v59, v38 \n v_mul_f32 v28, v60, v42 \n"  // inv2
        "v_mul_f32 v38, v41, v23 \n v_mul_f32 v42, v45, v27 \n"  // inv0 (tmp)
        "v_mul_f32 v23, v41, v22 \n v_mul_f32 v27, v45, v26 \n"  // inv1
        "v_mov_b32 v22, v38 \n v_mov_b32 v26, v42 \n"            // inv0
        // tanh = num * inv_den
        "v_mul_f32 v31, v31, v23 \n v_mul_f32 v33, v33, v25 \n"
        "v_mul_f32 v35, v35, v27 \n v_mul_f32 v37, v37, v29 \n"
        "v_mul_f32 v30, v30, v22 \n v_mul_f32 v32, v32, v24 \n"
        "v_mul_f32 v34, v34, v26 \n v_mul_f32 v36, v36, v28 \n"
        // pack tanh into f16 unit-pairs
        "v_cvt_pkrtz_f16_f32 v46, v30, v31 \n"
        "v_cvt_pkrtz_f16_f32 v47, v32, v33 \n"
        "v_cvt_pkrtz_f16_f32 v48, v34, v35 \n"
        "v_cvt_pkrtz_f16_f32 v49, v36, v37 \n"
        // g += tanh-pair . Qs-pair  (p outer, j inner)
        "v_dot2_f32_f16 v0, v46, v92,  v0 \n v_dot2_f32_f16 v1, v46, v93,  v1 \n"
        "v_dot2_f32_f16 v2, v46, v94,  v2 \n v_dot2_f32_f16 v3, v46, v95,  v3 \n"
        "v_dot2_f32_f16 v4, v46, v96,  v4 \n v_dot2_f32_f16 v5, v46, v97,  v5 \n"
        "v_dot2_f32_f16 v0, v47, v98,  v0 \n v_dot2_f32_f16 v1, v47, v99,  v1 \n"
        "v_dot2_f32_f16 v2, v47, v100, v2 \n v_dot2_f32_f16 v3, v47, v101, v3 \n"
        "v_dot2_f32_f16 v4, v47, v102, v4 \n v_dot2_f32_f16 v5, v47, v103, v5 \n"
        "v_dot2_f32_f16 v0, v48, v104, v0 \n v_dot2_f32_f16 v1, v48, v105, v1 \n"
        "v_dot2_f32_f16 v2, v48, v106, v2 \n v_dot2_f32_f16 v3, v48, v107, v3 \n"
        "v_dot2_f32_f16 v4, v48, v108, v4 \n v_dot2_f32_f16 v5, v48, v109, v5 \n"
        "v_dot2_f32_f16 v0, v49, v110, v0 \n v_dot2_f32_f16 v1, v49, v111, v1 \n"
        "v_dot2_f32_f16 v2, v49, v112, v2 \n v_dot2_f32_f16 v3, v49, v113, v3 \n"
        "v_dot2_f32_f16 v4, v49, v114, v4 \n v_dot2_f32_f16 v5, v49, v115, v5 \n"
        // 8-lane allreduce: xor1, xor2, xor7
        "v_add_f32_dpp v0, v0, v0 quad_perm:[1,0,3,2] row_mask:0xf bank_mask:0xf \n"
        "v_add_f32_dpp v1, v1, v1 quad_perm:[1,0,3,2] row_mask:0xf bank_mask:0xf \n"
        "v_add_f32_dpp v2, v2, v2 quad_perm:[1,0,3,2] row_mask:0xf bank_mask:0xf \n"
        "v_add_f32_dpp v3, v3, v3 quad_perm:[1,0,3,2] row_mask:0xf bank_mask:0xf \n"
        "v_add_f32_dpp v4, v4, v4 quad_perm:[1,0,3,2] row_mask:0xf bank_mask:0xf \n"
        "v_add_f32_dpp v5, v5, v5 quad_perm:[1,0,3,2] row_mask:0xf bank_mask:0xf \n"
        "v_add_f32_dpp v0, v0, v0 quad_perm:[2,3,0,1] row_mask:0xf bank_mask:0xf \n"
        "v_add_f32_dpp v1, v1, v1 quad_perm:[2,3,0,1] row_mask:0xf bank_mask:0xf \n"
        "v_add_f32_dpp v2, v2, v2 quad_perm:[2,3,0,1] row_mask:0xf bank_mask:0xf \n"
        "v_add_f32_dpp v3, v3, v3 quad_perm:[2,3,0,1] row_mask:0xf bank_mask:0xf \n"
        "v_add_f32_dpp v4, v4, v4 quad_perm:[2,3,0,1] row_mask:0xf bank_mask:0xf \n"
        "v_add_f32_dpp v5, v5, v5 quad_perm:[2,3,0,1] row_mask:0xf bank_mask:0xf \n"
        "v_add_f32_dpp v0, v0, v0 row_half_mirror row_mask:0xf bank_mask:0xf \n"
        "v_add_f32_dpp v1, v1, v1 row_half_mirror row_mask:0xf bank_mask:0xf \n"
        "v_add_f32_dpp v2, v2, v2 row_half_mirror row_mask:0xf bank_mask:0xf \n"
        "v_add_f32_dpp v3, v3, v3 row_half_mirror row_mask:0xf bank_mask:0xf \n"
        "v_add_f32_dpp v4, v4, v4 row_half_mirror row_mask:0xf bank_mask:0xf \n"
        "v_add_f32_dpp v5, v5, v5 row_half_mirror row_mask:0xf bank_mask:0xf \n"
        // u = med3(g, 0, 1)
        "v_med3_f32 v50, v0, 0, 1.0 \n v_med3_f32 v51, v1, 0, 1.0 \n"
        "v_med3_f32 v52, v2, 0, 1.0 \n v_med3_f32 v53, v3, 0, 1.0 \n"
        "v_med3_f32 v54, v4, 0, 1.0 \n v_med3_f32 v55, v5, 0, 1.0 \n"
        "s_sub_u32 s90, s90, 1 \n"
        "s_cmp_lg_u32 s90, 0 \n"
        "s_cbranch_scc1 L_step_%= \n"
        "v_mov_b32 %[o0], v50 \n v_mov_b32 %[o1], v51 \n v_mov_b32 %[o2], v52 \n"
        "v_mov_b32 %[o3], v53 \n v_mov_b32 %[o4], v54 \n v_mov_b32 %[o5], v55 \n"
        : [o0] "=v"(o0), [o1] "=v"(o1), [o2] "=v"(o2),
          [o3] "=v"(o3), [o4] "=v"(o4), [o5] "=v"(o5)
        : [pw] "v"(pw),
          [e0] "v"(ec[0]), [e1] "v"(ec[1]), [e2] "v"(ec[2]),
          [e3] "v"(ec[3]), [e4] "v"(ec[4]), [e5] "v"(ec[5])
        : "v0","v1","v2","v3","v4","v5","v6","v7","v8","v9","v10","v11","v12",
          "v13","v14","v15","v16","v17","v18","v19","v20","v21","v22","v23",
          "v24","v25","v26","v27","v28","v29","v30","v31","v32","v33","v34",
          "v35","v36","v37","v38","v39","v40","v41","v42","v43","v44","v45",
          "v46","v47","v48","v49","v50","v51","v52","v53","v54","v55","v56",
          "v57","v58","v59","v60","v61","v62","v63","v64","v65","v66","v67",
          "v68","v69","v70","v71","v72","v73","v74","v75","v76","v77","v78",
          "v79","v80","v81","v82","v83","v84","v85","v86","v87","v88","v89",
          "v90","v91","v92","v93","v94","v95","v96","v97","v98","v99","v100",
          "v101","v102","v103","v104","v105","v106","v107","v108","v109",
          "v110","v111","v112","v113","v114","v115","v116","v117","v118",
          "v119","v120","v121","v122","v123","v124",
          "s90","scc");

    if (live && sub == 0) {
        float* o = out + s * 6;
        o[0] = o0; o[1] = o1; o[2] = o2; o[3] = o3; o[4] = o4; o[5] = o5;
    }
}

extern "C" void kernel_launch(void* const* d_in, const int* in_sizes, int n_in,
                              void* d_out, int out_size, void* d_ws, size_t ws_size,
                              hipStream_t stream)
{
    const float* spec = (const float*)d_in[0];  // (B,40)
    const float* W1   = (const float*)d_in[1];  // (6,64)
    const float* b1   = (const float*)d_in[2];  // (64,)
    const float* W2   = (const float*)d_in[3];  // (64,40)
    const float* b2   = (const float*)d_in[4];  // (40,)
    const float* R    = (const float*)d_in[5];  // (8,40)
    unsigned int* ws  = (unsigned int*)d_ws;
    int batch = in_sizes[0] / 40;

    hipLaunchKernelGGL(setup_k, dim3(1), dim3(128), 0, stream, W1, b1, W2, b2, R, ws);

    int threads = batch * 8;
    int blocks  = (threads + 255) / 256;
    hipLaunchKernelGGL(solve_k, dim3(blocks), dim3(256), 0, stream,
                       spec, R, ws, (float*)d_out, batch);
}

// Round 8
// 157.103 us; speedup vs baseline: 1.2005x; 1.2005x over previous
//
#include <hip/hip_runtime.h>

// BackwardRPM: 16384 solves x 200 steps:
//   u <- clip(u - LR*(R^T(R(tanh(u W1+b1) W2 + b2 - spec)))[:6], 0, 1)
// Algebra (as R6): Qs = -LR*W2 R^T R6; es = -LR*R6^T R(b2-spec);
//   tanh = 1-2r, r = rcp(exp2(K(uW1+b1))+1), K=2log2e (K folded into W1,b1);
//   u <- med3(u + es + sum_i Qs[i,:] + sum_i r_i*(-2Qs[i,:]), 0, 1).
//
// R8 = R6 hand-asm skeleton (no remat, 0 LDS) + v_pk_fma_f32 (CDNA4 packed
// fp32 = 2 FMA/issue-slot; MI355X's 157.3TF spec requires it) + 4 lanes/sample
// (16 units/lane; only 2 DPP reduce stages; per-sample overhead halves).
// u broadcast into both pk halves via op_sel_hi:[0,1,1] (no dup movs).
// 1024 waves = 1/SIMD; R1 showed 83% VALUBusy at 1 wave via in-wave ILP.
//
// ws float layout, slice per sub (stride 256, sub=0..3, units ib=16*sub..+15):
//  [0..95]    w1 pairs: [(p*6+j)*2+h] = K*W1[j][ib+2p+h]
//  [96..111]  b1: [96+loc] = K*b1[ib+loc]
//  [112..207] q pairs: [112+(j*8+p)*2+h] = -2*Qs[ib+2p+h][j]
//  [208..213] qsum_j = sum_{own 16 units} Qs[i][j]
//  [1024..1031] (R b2)[p];  [1032..1415] scratch (raw Qs for qsum pass)

static constexpr float LR_ = 0.01f;

__global__ void setup_k(const float* __restrict__ W1, const float* __restrict__ b1,
                        const float* __restrict__ W2, const float* __restrict__ b2,
                        const float* __restrict__ R,  float* __restrict__ ws)
{
    const float K = 2.8853900817779268f;  // 2*log2(e)
    const int i = threadIdx.x;            // 64 threads
    if (i < 64) {
        float M[8];
        #pragma unroll
        for (int p = 0; p < 8; ++p) {
            float acc = 0.f;
            for (int k = 0; k < 40; ++k) acc = fmaf(W2[i*40+k], R[p*40+k], acc);
            M[p] = acc;
        }
        const int sub = i >> 4, loc = i & 15, p2 = loc >> 1, h = loc & 1;
        float* sl = ws + sub * 256;
        #pragma unroll
        for (int j = 0; j < 6; ++j) {
            float acc = 0.f;
            #pragma unroll
            for (int p = 0; p < 8; ++p) acc = fmaf(M[p], R[p*40+j], acc);
            float q = -LR_ * acc;                      // Qs[i][j]
            sl[(p2*6 + j)*2 + h]       = K * W1[j*64 + i];
            sl[112 + (j*8 + p2)*2 + h] = -2.f * q;
            ws[1032 + i*6 + j] = q;
        }
        sl[96 + loc] = K * b1[i];
    }
    __syncthreads();
    if (i < 24) {
        const int sub = i / 6, j = i % 6;
        float acc = 0.f;
        for (int loc = 0; loc < 16; ++loc) acc += ws[1032 + (sub*16 + loc)*6 + j];
        ws[sub*256 + 208 + j] = acc;
    }
    if (i >= 32 && i < 40) {
        const int p = i - 32;
        float acc = 0.f;
        for (int k = 0; k < 40; ++k) acc = fmaf(R[p*40+k], b2[k], acc);
        ws[1024 + p] = acc;
    }
}

__global__ __launch_bounds__(256)
__attribute__((amdgpu_waves_per_eu(1, 1)))
void solve_k(const float* __restrict__ spec, const float* __restrict__ R,
             const float* __restrict__ ws,   float* __restrict__ out, int batch)
{
    const int tid = blockIdx.x * 256 + threadIdx.x;
    const int s   = tid >> 2;
    const int sub = tid & 3;
    const bool live = (s < batch);
    const int sl = live ? s : 0;
    const float* slice = ws + sub * 256;

    // z[p] = (R b2)[p] - sum_k R[p][k] spec[k]
    float z[8];
    #pragma unroll
    for (int p = 0; p < 8; ++p) z[p] = ws[1024 + p];
    const float* sp = spec + sl * 40;
    for (int k = 0; k < 40; ++k) {
        float v = sp[k];
        #pragma unroll
        for (int p = 0; p < 8; ++p) z[p] = fmaf(-R[p*40+k], v, z[p]);
    }
    // ecl[j] = 0.25*es[j] + qsum[j],  es = -LR * R6^T z
    float ecl[6];
    #pragma unroll
    for (int j = 0; j < 6; ++j) {
        float acc = 0.f;
        #pragma unroll
        for (int p = 0; p < 8; ++p) acc = fmaf(R[p*40+j], z[p], acc);
        ecl[j] = fmaf(-LR_ * 0.25f, acc, slice[208 + j]);
    }

    const float* pw = slice;
    float o0, o1, o2, o3, o4, o5;
    // Register map (hard regs):
    //  v[2p:2p+1]   p=0..7: t/r unit-pair values        (v0..v15)
    //  v16+2j       u_j (odd partners unused/ignored)
    //  v[28+2j:+1]  g accumulator pairs                  (v28..v39)
    //  v[40+(p*6+j)*2]  K*W1 pairs   (v40..v135)
    //  v[136+2p]    K*b1 pairs       (v136..v151)
    //  v[152+(j*8+p)*2] -2Qs pairs   (v152..v247)
    //  s90 loop ctr, s91 = 0.25
    asm volatile(
        // ---- constant loads ----
        "global_load_dwordx4 v[40:43],   %[pw], off            \n"
        "global_load_dwordx4 v[44:47],   %[pw], off offset:16  \n"
        "global_load_dwordx4 v[48:51],   %[pw], off offset:32  \n"
        "global_load_dwordx4 v[52:55],   %[pw], off offset:48  \n"
        "global_load_dwordx4 v[56:59],   %[pw], off offset:64  \n"
        "global_load_dwordx4 v[60:63],   %[pw], off offset:80  \n"
        "global_load_dwordx4 v[64:67],   %[pw], off offset:96  \n"
        "global_load_dwordx4 v[68:71],   %[pw], off offset:112 \n"
        "global_load_dwordx4 v[72:75],   %[pw], off offset:128 \n"
        "global_load_dwordx4 v[76:79],   %[pw], off offset:144 \n"
        "global_load_dwordx4 v[80:83],   %[pw], off offset:160 \n"
        "global_load_dwordx4 v[84:87],   %[pw], off offset:176 \n"
        "global_load_dwordx4 v[88:91],   %[pw], off offset:192 \n"
        "global_load_dwordx4 v[92:95],   %[pw], off offset:208 \n"
        "global_load_dwordx4 v[96:99],   %[pw], off offset:224 \n"
        "global_load_dwordx4 v[100:103], %[pw], off offset:240 \n"
        "global_load_dwordx4 v[104:107], %[pw], off offset:256 \n"
        "global_load_dwordx4 v[108:111], %[pw], off offset:272 \n"
        "global_load_dwordx4 v[112:115], %[pw], off offset:288 \n"
        "global_load_dwordx4 v[116:119], %[pw], off offset:304 \n"
        "global_load_dwordx4 v[120:123], %[pw], off offset:320 \n"
        "global_load_dwordx4 v[124:127], %[pw], off offset:336 \n"
        "global_load_dwordx4 v[128:131], %[pw], off offset:352 \n"
        "global_load_dwordx4 v[132:135], %[pw], off offset:368 \n"
        "global_load_dwordx4 v[136:139], %[pw], off offset:384 \n"
        "global_load_dwordx4 v[140:143], %[pw], off offset:400 \n"
        "global_load_dwordx4 v[144:147], %[pw], off offset:416 \n"
        "global_load_dwordx4 v[148:151], %[pw], off offset:432 \n"
        "global_load_dwordx4 v[152:155], %[pw], off offset:448 \n"
        "global_load_dwordx4 v[156:159], %[pw], off offset:464 \n"
        "global_load_dwordx4 v[160:163], %[pw], off offset:480 \n"
        "global_load_dwordx4 v[164:167], %[pw], off offset:496 \n"
        "global_load_dwordx4 v[168:171], %[pw], off offset:512 \n"
        "global_load_dwordx4 v[172:175], %[pw], off offset:528 \n"
        "global_load_dwordx4 v[176:179], %[pw], off offset:544 \n"
        "global_load_dwordx4 v[180:183], %[pw], off offset:560 \n"
        "global_load_dwordx4 v[184:187], %[pw], off offset:576 \n"
        "global_load_dwordx4 v[188:191], %[pw], off offset:592 \n"
        "global_load_dwordx4 v[192:195], %[pw], off offset:608 \n"
        "global_load_dwordx4 v[196:199], %[pw], off offset:624 \n"
        "global_load_dwordx4 v[200:203], %[pw], off offset:640 \n"
        "global_load_dwordx4 v[204:207], %[pw], off offset:656 \n"
        "global_load_dwordx4 v[208:211], %[pw], off offset:672 \n"
        "global_load_dwordx4 v[212:215], %[pw], off offset:688 \n"
        "global_load_dwordx4 v[216:219], %[pw], off offset:704 \n"
        "global_load_dwordx4 v[220:223], %[pw], off offset:720 \n"
        "global_load_dwordx4 v[224:227], %[pw], off offset:736 \n"
        "global_load_dwordx4 v[228:231], %[pw], off offset:752 \n"
        "global_load_dwordx4 v[232:235], %[pw], off offset:768 \n"
        "global_load_dwordx4 v[236:239], %[pw], off offset:784 \n"
        "global_load_dwordx4 v[240:243], %[pw], off offset:800 \n"
        "global_load_dwordx4 v[244:247], %[pw], off offset:816 \n"
        "v_mov_b32 v16, 0.5 \n v_mov_b32 v18, 0.5 \n v_mov_b32 v20, 0.5 \n"
        "v_mov_b32 v22, 0.5 \n v_mov_b32 v24, 0.5 \n v_mov_b32 v26, 0.5 \n"
        "s_mov_b32 s91, 0x3e800000 \n"   // 0.25
        "s_mov_b32 s90, 200 \n"
        "s_waitcnt vmcnt(0) \n"
        "L_step_%=: \n"
        // ---- t = K*(u W1 + b1): 48 pk_fma, u-lo broadcast to both halves ----
        "v_pk_fma_f32 v[0:1],   v[16:17], v[40:41],   v[136:137] op_sel:[0,0,0] op_sel_hi:[0,1,1] \n"
        "v_pk_fma_f32 v[2:3],   v[16:17], v[52:53],   v[138:139] op_sel:[0,0,0] op_sel_hi:[0,1,1] \n"
        "v_pk_fma_f32 v[4:5],   v[16:17], v[64:65],   v[140:141] op_sel:[0,0,0] op_sel_hi:[0,1,1] \n"
        "v_pk_fma_f32 v[6:7],   v[16:17], v[76:77],   v[142:143] op_sel:[0,0,0] op_sel_hi:[0,1,1] \n"
        "v_pk_fma_f32 v[8:9],   v[16:17], v[88:89],   v[144:145] op_sel:[0,0,0] op_sel_hi:[0,1,1] \n"
        "v_pk_fma_f32 v[10:11], v[16:17], v[100:101], v[146:147] op_sel:[0,0,0] op_sel_hi:[0,1,1] \n"
        "v_pk_fma_f32 v[12:13], v[16:17], v[112:113], v[148:149] op_sel:[0,0,0] op_sel_hi:[0,1,1] \n"
        "v_pk_fma_f32 v[14:15], v[16:17], v[124:125], v[150:151] op_sel:[0,0,0] op_sel_hi:[0,1,1] \n"
        "v_pk_fma_f32 v[0:1],   v[18:19], v[42:43],   v[0:1]   op_sel:[0,0,0] op_sel_hi:[0,1,1] \n"
        "v_pk_fma_f32 v[2:3],   v[18:19], v[54:55],   v[2:3]   op_sel:[0,0,0] op_sel_hi:[0,1,1] \n"
        "v_pk_fma_f32 v[4:5],   v[18:19], v[66:67],   v[4:5]   op_sel:[0,0,0] op_sel_hi:[0,1,1] \n"
        "v_pk_fma_f32 v[6:7],   v[18:19], v[78:79],   v[6:7]   op_sel:[0,0,0] op_sel_hi:[0,1,1] \n"
        "v_pk_fma_f32 v[8:9],   v[18:19], v[90:91],   v[8:9]   op_sel:[0,0,0] op_sel_hi:[0,1,1] \n"
        "v_pk_fma_f32 v[10:11], v[18:19], v[102:103], v[10:11] op_sel:[0,0,0] op_sel_hi:[0,1,1] \n"
        "v_pk_fma_f32 v[12:13], v[18:19], v[114:115], v[12:13] op_sel:[0,0,0] op_sel_hi:[0,1,1] \n"
        "v_pk_fma_f32 v[14:15], v[18:19], v[126:127], v[14:15] op_sel:[0,0,0] op_sel_hi:[0,1,1] \n"
        "v_pk_fma_f32 v[0:1],   v[20:21], v[44:45],   v[0:1]   op_sel:[0,0,0] op_sel_hi:[0,1,1] \n"
        "v_pk_fma_f32 v[2:3],   v[20:21], v[56:57],   v[2:3]   op_sel:[0,0,0] op_sel_hi:[0,1,1] \n"
        "v_pk_fma_f32 v[4:5],   v[20:21], v[68:69],   v[4:5]   op_sel:[0,0,0] op_sel_hi:[0,1,1] \n"
        "v_pk_fma_f32 v[6:7],   v[20:21], v[80:81],   v[6:7]   op_sel:[0,0,0] op_sel_hi:[0,1,1] \n"
        "v_pk_fma_f32 v[8:9],   v[20:21], v[92:93],   v[8:9]   op_sel:[0,0,0] op_sel_hi:[0,1,1] \n"
        "v_pk_fma_f32 v[10:11], v[20:21], v[104:105], v[10:11] op_sel:[0,0,0] op_sel_hi:[0,1,1] \n"
        "v_pk_fma_f32 v[12:13], v[20:21], v[116:117], v[12:13] op_sel:[0,0,0] op_sel_hi:[0,1,1] \n"
        "v_pk_fma_f32 v[14:15], v[20:21], v[128:129], v[14:15] op_sel:[0,0,0] op_sel_hi:[0,1,1] \n"
        "v_pk_fma_f32 v[0:1],   v[22:23], v[46:47],   v[0:1]   op_sel:[0,0,0] op_sel_hi:[0,1,1] \n"
        "v_pk_fma_f32 v[2:3],   v[22:23], v[58:59],   v[2:3]   op_sel:[0,0,0] op_sel_hi:[0,1,1] \n"
        "v_pk_fma_f32 v[4:5],   v[22:23], v[70:71],   v[4:5]   op_sel:[0,0,0] op_sel_hi:[0,1,1] \n"
        "v_pk_fma_f32 v[6:7],   v[22:23], v[82:83],   v[6:7]   op_sel:[0,0,0] op_sel_hi:[0,1,1] \n"
        "v_pk_fma_f32 v[8:9],   v[22:23], v[94:95],   v[8:9]   op_sel:[0,0,0] op_sel_hi:[0,1,1] \n"
        "v_pk_fma_f32 v[10:11], v[22:23], v[106:107], v[10:11] op_sel:[0,0,0] op_sel_hi:[0,1,1] \n"
        "v_pk_fma_f32 v[12:13], v[22:23], v[118:119], v[12:13] op_sel:[0,0,0] op_sel_hi:[0,1,1] \n"
        "v_pk_fma_f32 v[14:15], v[22:23], v[130:131], v[14:15] op_sel:[0,0,0] op_sel_hi:[0,1,1] \n"
        "v_pk_fma_f32 v[0:1],   v[24:25], v[48:49],   v[0:1]   op_sel:[0,0,0] op_sel_hi:[0,1,1] \n"
        "v_pk_fma_f32 v[2:3],   v[24:25], v[60:61],   v[2:3]   op_sel:[0,0,0] op_sel_hi:[0,1,1] \n"
        "v_pk_fma_f32 v[4:5],   v[24:25], v[72:73],   v[4:5]   op_sel:[0,0,0] op_sel_hi:[0,1,1] \n"
        "v_pk_fma_f32 v[6:7],   v[24:25], v[84:85],   v[6:7]   op_sel:[0,0,0] op_sel_hi:[0,1,1] \n"
        "v_pk_fma_f32 v[8:9],   v[24:25], v[96:97],   v[8:9]   op_sel:[0,0,0] op_sel_hi:[0,1,1] \n"
        "v_pk_fma_f32 v[10:11], v[24:25], v[108:109], v[10:11] op_sel:[0,0,0] op_sel_hi:[0,1,1] \n"
        "v_pk_fma_f32 v[12:13], v[24:25], v[120:121], v[12:13] op_sel:[0,0,0] op_sel_hi:[0,1,1] \n"
        "v_pk_fma_f32 v[14:15], v[24:25], v[132:133], v[14:15] op_sel:[0,0,0] op_sel_hi:[0,1,1] \n"
        "v_pk_fma_f32 v[0:1],   v[26:27], v[50:51],   v[0:1]   op_sel:[0,0,0] op_sel_hi:[0,1,1] \n"
        "v_pk_fma_f32 v[2:3],   v[26:27], v[62:63],   v[2:3]   op_sel:[0,0,0] op_sel_hi:[0,1,1] \n"
        "v_pk_fma_f32 v[4:5],   v[26:27], v[74:75],   v[4:5]   op_sel:[0,0,0] op_sel_hi:[0,1,1] \n"
        "v_pk_fma_f32 v[6:7],   v[26:27], v[86:87],   v[6:7]   op_sel:[0,0,0] op_sel_hi:[0,1,1] \n"
        "v_pk_fma_f32 v[8:9],   v[26:27], v[98:99],   v[8:9]   op_sel:[0,0,0] op_sel_hi:[0,1,1] \n"
        "v_pk_fma_f32 v[10:11], v[26:27], v[110:111], v[10:11] op_sel:[0,0,0] op_sel_hi:[0,1,1] \n"
        "v_pk_fma_f32 v[12:13], v[26:27], v[122:123], v[12:13] op_sel:[0,0,0] op_sel_hi:[0,1,1] \n"
        "v_pk_fma_f32 v[14:15], v[26:27], v[134:135], v[14:15] op_sel:[0,0,0] op_sel_hi:[0,1,1] \n"
        // ---- r = rcp(exp2(t)+1) ----
        "v_exp_f32 v0, v0   \n v_exp_f32 v1, v1   \n v_exp_f32 v2, v2   \n v_exp_f32 v3, v3   \n"
        "v_exp_f32 v4, v4   \n v_exp_f32 v5, v5   \n v_exp_f32 v6, v6   \n v_exp_f32 v7, v7   \n"
        "v_exp_f32 v8, v8   \n v_exp_f32 v9, v9   \n v_exp_f32 v10, v10 \n v_exp_f32 v11, v11 \n"
        "v_exp_f32 v12, v12 \n v_exp_f32 v13, v13 \n v_exp_f32 v14, v14 \n v_exp_f32 v15, v15 \n"
        "v_add_f32 v0, 1.0, v0   \n v_add_f32 v1, 1.0, v1   \n v_add_f32 v2, 1.0, v2   \n"
        "v_add_f32 v3, 1.0, v3   \n v_add_f32 v4, 1.0, v4   \n v_add_f32 v5, 1.0, v5   \n"
        "v_add_f32 v6, 1.0, v6   \n v_add_f32 v7, 1.0, v7   \n v_add_f32 v8, 1.0, v8   \n"
        "v_add_f32 v9, 1.0, v9   \n v_add_f32 v10, 1.0, v10 \n v_add_f32 v11, 1.0, v11 \n"
        "v_add_f32 v12, 1.0, v12 \n v_add_f32 v13, 1.0, v13 \n v_add_f32 v14, 1.0, v14 \n"
        "v_add_f32 v15, 1.0, v15 \n"
        "v_rcp_f32 v0, v0   \n v_rcp_f32 v1, v1   \n v_rcp_f32 v2, v2   \n v_rcp_f32 v3, v3   \n"
        "v_rcp_f32 v4, v4   \n v_rcp_f32 v5, v5   \n v_rcp_f32 v6, v6   \n v_rcp_f32 v7, v7   \n"
        "v_rcp_f32 v8, v8   \n v_rcp_f32 v9, v9   \n v_rcp_f32 v10, v10 \n v_rcp_f32 v11, v11 \n"
        "v_rcp_f32 v12, v12 \n v_rcp_f32 v13, v13 \n v_rcp_f32 v14, v14 \n v_rcp_f32 v15, v15 \n"
        // ---- g pairs += r_pair * (-2Qs)_pair : 48 pk ops (p outer, j inner) ----
        "v_pk_mul_f32 v[28:29], v[0:1], v[152:153] \n"
        "v_pk_mul_f32 v[30:31], v[0:1], v[168:169] \n"
        "v_pk_mul_f32 v[32:33], v[0:1], v[184:185] \n"
        "v_pk_mul_f32 v[34:35], v[0:1], v[200:201] \n"
        "v_pk_mul_f32 v[36:37], v[0:1], v[216:217] \n"
        "v_pk_mul_f32 v[38:39], v[0:1], v[232:233] \n"
        "v_pk_fma_f32 v[28:29], v[2:3], v[154:155], v[28:29] \n"
        "v_pk_fma_f32 v[30:31], v[2:3], v[170:171], v[30:31] \n"
        "v_pk_fma_f32 v[32:33], v[2:3], v[186:187], v[32:33] \n"
        "v_pk_fma_f32 v[34:35], v[2:3], v[202:203], v[34:35] \n"
        "v_pk_fma_f32 v[36:37], v[2:3], v[218:219], v[36:37] \n"
        "v_pk_fma_f32 v[38:39], v[2:3], v[234:235], v[38:39] \n"
        "v_pk_fma_f32 v[28:29], v[4:5], v[156:157], v[28:29] \n"
        "v_pk_fma_f32 v[30:31], v[4:5], v[172:173], v[30:31] \n"
        "v_pk_fma_f32 v[32:33], v[4:5], v[188:189], v[32:33] \n"
        "v_pk_fma_f32 v[34:35], v[4:5], v[204:205], v[34:35] \n"
        "v_pk_fma_f32 v[36:37], v[4:5], v[220:221], v[36:37] \n"
        "v_pk_fma_f32 v[38:39], v[4:5], v[236:237], v[38:39] \n"
        "v_pk_fma_f32 v[28:29], v[6:7], v[158:159], v[28:29] \n"
        "v_pk_fma_f32 v[30:31], v[6:7], v[174:175], v[30:31] \n"
        "v_pk_fma_f32 v[32:33], v[6:7], v[190:191], v[32:33] \n"
        "v_pk_fma_f32 v[34:35], v[6:7], v[206:207], v[34:35] \n"
        "v_pk_fma_f32 v[36:37], v[6:7], v[222:223], v[36:37] \n"
        "v_pk_fma_f32 v[38:39], v[6:7], v[238:239], v[38:39] \n"
        "v_pk_fma_f32 v[28:29], v[8:9], v[160:161], v[28:29] \n"
        "v_pk_fma_f32 v[30:31], v[8:9], v[176:177], v[30:31] \n"
        "v_pk_fma_f32 v[32:33], v[8:9], v[192:193], v[32:33] \n"
        "v_pk_fma_f32 v[34:35], v[8:9], v[208:209], v[34:35] \n"
        "v_pk_fma_f32 v[36:37], v[8:9], v[224:225], v[36:37] \n"
        "v_pk_fma_f32 v[38:39], v[8:9], v[240:241], v[38:39] \n"
        "v_pk_fma_f32 v[28:29], v[10:11], v[162:163], v[28:29] \n"
        "v_pk_fma_f32 v[30:31], v[10:11], v[178:179], v[30:31] \n"
        "v_pk_fma_f32 v[32:33], v[10:11], v[194:195], v[32:33] \n"
        "v_pk_fma_f32 v[34:35], v[10:11], v[210:211], v[34:35] \n"
        "v_pk_fma_f32 v[36:37], v[10:11], v[226:227], v[36:37] \n"
        "v_pk_fma_f32 v[38:39], v[10:11], v[242:243], v[38:39] \n"
        "v_pk_fma_f32 v[28:29], v[12:13], v[164:165], v[28:29] \n"
        "v_pk_fma_f32 v[30:31], v[12:13], v[180:181], v[30:31] \n"
        "v_pk_fma_f32 v[32:33], v[12:13], v[196:197], v[32:33] \n"
        "v_pk_fma_f32 v[34:35], v[12:13], v[212:213], v[34:35] \n"
        "v_pk_fma_f32 v[36:37], v[12:13], v[228:229], v[36:37] \n"
        "v_pk_fma_f32 v[38:39], v[12:13], v[244:245], v[38:39] \n"
        "v_pk_fma_f32 v[28:29], v[14:15], v[166:167], v[28:29] \n"
        "v_pk_fma_f32 v[30:31], v[14:15], v[182:183], v[30:31] \n"
        "v_pk_fma_f32 v[32:33], v[14:15], v[198:199], v[32:33] \n"
        "v_pk_fma_f32 v[34:35], v[14:15], v[214:215], v[34:35] \n"
        "v_pk_fma_f32 v[36:37], v[14:15], v[230:231], v[36:37] \n"
        "v_pk_fma_f32 v[38:39], v[14:15], v[246:247], v[38:39] \n"
        // ---- collapse hi+lo, add init = 0.25*u + ecl ----
        "v_add_f32 v28, v28, v29 \n v_add_f32 v30, v30, v31 \n v_add_f32 v32, v32, v33 \n"
        "v_add_f32 v34, v34, v35 \n v_add_f32 v36, v36, v37 \n v_add_f32 v38, v38, v39 \n"
        "v_fma_f32 v29, s91, v16, %[e0] \n v_fma_f32 v31, s91, v18, %[e1] \n"
        "v_fma_f32 v33, s91, v20, %[e2] \n v_fma_f32 v35, s91, v22, %[e3] \n"
        "v_fma_f32 v37, s91, v24, %[e4] \n v_fma_f32 v39, s91, v26, %[e5] \n"
        "v_add_f32 v28, v28, v29 \n v_add_f32 v30, v30, v31 \n v_add_f32 v32, v32, v33 \n"
        "v_add_f32 v34, v34, v35 \n v_add_f32 v36, v36, v37 \n v_add_f32 v38, v38, v39 \n"
        // ---- 4-lane allreduce (quad): xor1, xor2 ----
        "v_add_f32_dpp v28, v28, v28 quad_perm:[1,0,3,2] row_mask:0xf bank_mask:0xf \n"
        "v_add_f32_dpp v30, v30, v30 quad_perm:[1,0,3,2] row_mask:0xf bank_mask:0xf \n"
        "v_add_f32_dpp v32, v32, v32 quad_perm:[1,0,3,2] row_mask:0xf bank_mask:0xf \n"
        "v_add_f32_dpp v34, v34, v34 quad_perm:[1,0,3,2] row_mask:0xf bank_mask:0xf \n"
        "v_add_f32_dpp v36, v36, v36 quad_perm:[1,0,3,2] row_mask:0xf bank_mask:0xf \n"
        "v_add_f32_dpp v38, v38, v38 quad_perm:[1,0,3,2] row_mask:0xf bank_mask:0xf \n"
        "v_add_f32_dpp v28, v28, v28 quad_perm:[2,3,0,1] row_mask:0xf bank_mask:0xf \n"
        "v_add_f32_dpp v30, v30, v30 quad_perm:[2,3,0,1] row_mask:0xf bank_mask:0xf \n"
        "v_add_f32_dpp v32, v32, v32 quad_perm:[2,3,0,1] row_mask:0xf bank_mask:0xf \n"
        "v_add_f32_dpp v34, v34, v34 quad_perm:[2,3,0,1] row_mask:0xf bank_mask:0xf \n"
        "v_add_f32_dpp v36, v36, v36 quad_perm:[2,3,0,1] row_mask:0xf bank_mask:0xf \n"
        "v_add_f32_dpp v38, v38, v38 quad_perm:[2,3,0,1] row_mask:0xf bank_mask:0xf \n"
        // ---- u = med3(g, 0, 1) ----
        "v_med3_f32 v16, v28, 0, 1.0 \n v_med3_f32 v18, v30, 0, 1.0 \n"
        "v_med3_f32 v20, v32, 0, 1.0 \n v_med3_f32 v22, v34, 0, 1.0 \n"
        "v_med3_f32 v24, v36, 0, 1.0 \n v_med3_f32 v26, v38, 0, 1.0 \n"
        "s_sub_u32 s90, s90, 1 \n"
        "s_cmp_lg_u32 s90, 0 \n"
        "s_cbranch_scc1 L_step_%= \n"
        "v_mov_b32 %[o0], v16 \n v_mov_b32 %[o1], v18 \n v_mov_b32 %[o2], v20 \n"
        "v_mov_b32 %[o3], v22 \n v_mov_b32 %[o4], v24 \n v_mov_b32 %[o5], v26 \n"
        : [o0] "=v"(o0), [o1] "=v"(o1), [o2] "=v"(o2),
          [o3] "=v"(o3), [o4] "=v"(o4), [o5] "=v"(o5)
        : [pw] "v"(pw),
          [e0] "v"(ecl[0]), [e1] "v"(ecl[1]), [e2] "v"(ecl[2]),
          [e3] "v"(ecl[3]), [e4] "v"(ecl[4]), [e5] "v"(ecl[5])
        : "v0","v1","v2","v3","v4","v5","v6","v7","v8","v9","v10","v11","v12",
          "v13","v14","v15","v16","v18","v20","v22","v24","v26",
          "v28","v29","v30","v31","v32","v33","v34","v35","v36","v37","v38","v39",
          "v40","v41","v42","v43","v44","v45","v46","v47","v48","v49","v50",
          "v51","v52","v53","v54","v55","v56","v57","v58","v59","v60","v61",
          "v62","v63","v64","v65","v66","v67","v68","v69","v70","v71","v72",
          "v73","v74","v75","v76","v77","v78","v79","v80","v81","v82","v83",
          "v84","v85","v86","v87","v88","v89","v90","v91","v92","v93","v94",
          "v95","v96","v97","v98","v99","v100","v101","v102","v103","v104",
          "v105","v106","v107","v108","v109","v110","v111","v112","v113",
          "v114","v115","v116","v117","v118","v119","v120","v121","v122",
          "v123","v124","v125","v126","v127","v128","v129","v130","v131",
          "v132","v133","v134","v135","v136","v137","v138","v139","v140",
          "v141","v142","v143","v144","v145","v146","v147","v148","v149",
          "v150","v151","v152","v153","v154","v155","v156","v157","v158",
          "v159","v160","v161","v162","v163","v164","v165","v166","v167",
          "v168","v169","v170","v171","v172","v173","v174","v175","v176",
          "v177","v178","v179","v180","v181","v182","v183","v184","v185",
          "v186","v187","v188","v189","v190","v191","v192","v193","v194",
          "v195","v196","v197","v198","v199","v200","v201","v202","v203",
          "v204","v205","v206","v207","v208","v209","v210","v211","v212",
          "v213","v214","v215","v216","v217","v218","v219","v220","v221",
          "v222","v223","v224","v225","v226","v227","v228","v229","v230",
          "v231","v232","v233","v234","v235","v236","v237","v238","v239",
          "v240","v241","v242","v243","v244","v245","v246","v247",
          "s90","s91","scc");

    if (live && sub == 0) {
        float* o = out + s * 6;
        o[0] = o0; o[1] = o1; o[2] = o2; o[3] = o3; o[4] = o4; o[5] = o5;
    }
}

extern "C" void kernel_launch(void* const* d_in, const int* in_sizes, int n_in,
                              void* d_out, int out_size, void* d_ws, size_t ws_size,
                              hipStream_t stream)
{
    const float* spec = (const float*)d_in[0];  // (B,40)
    const float* W1   = (const float*)d_in[1];  // (6,64)
    const float* b1   = (const float*)d_in[2];  // (64,)
    const float* W2   = (const float*)d_in[3];  // (64,40)
    const float* b2   = (const float*)d_in[4];  // (40,)
    const float* R    = (const float*)d_in[5];  // (8,40)
    float* ws = (float*)d_ws;
    int batch = in_sizes[0] / 40;

    hipLaunchKernelGGL(setup_k, dim3(1), dim3(64), 0, stream, W1, b1, W2, b2, R, ws);

    int threads = batch * 4;
    int blocks  = (threads + 255) / 256;
    hipLaunchKernelGGL(solve_k, dim3(blocks), dim3(256), 0, stream,
                       spec, R, ws, (float*)d_out, batch);
}